// Round 1
// baseline (1152.728 us; speedup 1.0000x reference)
//
#include <hip/hip_runtime.h>
#include <hip/hip_bf16.h>
#include <math.h>

#define NN 100000
#define EE 1600000
#define FF 128
#define HH 64
#define CC 40

constexpr int SCAN_B = 1024;
constexpr int NB = (NN + SCAN_B - 1) / SCAN_B;  // 98

// ---------------- degree / norm ----------------
__global__ void k_init_deg(int* __restrict__ deg) {
    int i = blockIdx.x * 256 + threadIdx.x;
    if (i < NN) deg[i] = 1;  // self-loop contributes 1
}

__global__ void k_count(const int* __restrict__ ei, int* __restrict__ deg) {
    int e = blockIdx.x * 256 + threadIdx.x;
    if (e < EE) atomicAdd(&deg[ei[EE + e]], 1);
}

__global__ void k_dinv(const int* __restrict__ deg, float* __restrict__ dinv) {
    int i = blockIdx.x * 256 + threadIdx.x;
    if (i < NN) dinv[i] = rsqrtf((float)deg[i]);  // deg >= 1 always
}

// ---------------- exclusive scan (3-kernel) ----------------
__global__ void k_scanA(const int* __restrict__ deg, int* __restrict__ excl, int* __restrict__ bsum) {
    __shared__ int s[SCAN_B];
    int t = threadIdx.x;
    int g = blockIdx.x * SCAN_B + t;
    int v = (g < NN) ? deg[g] : 0;
    s[t] = v;
    __syncthreads();
    for (int o = 1; o < SCAN_B; o <<= 1) {
        int u = (t >= o) ? s[t - o] : 0;
        __syncthreads();
        s[t] += u;
        __syncthreads();
    }
    if (g < NN) excl[g] = s[t] - v;
    if (t == SCAN_B - 1) bsum[blockIdx.x] = s[t];
}

__global__ void k_scanB(int* __restrict__ bsum) {
    __shared__ int s[128];
    int t = threadIdx.x;
    int v = (t < NB) ? bsum[t] : 0;
    s[t] = v;
    __syncthreads();
    for (int o = 1; o < 128; o <<= 1) {
        int u = (t >= o) ? s[t - o] : 0;
        __syncthreads();
        s[t] += u;
        __syncthreads();
    }
    if (t < NB) bsum[t] = s[t] - v;  // exclusive block offsets
}

__global__ void k_scanC(int* __restrict__ rp, const int* __restrict__ bsum, int* __restrict__ cursor) {
    int t = threadIdx.x;
    int g = blockIdx.x * SCAN_B + t;
    if (g < NN) {
        int v = rp[g] + bsum[blockIdx.x];
        rp[g] = v;
        cursor[g] = v;
    }
    if (g == 0) rp[NN] = EE + NN;
}

// ---------------- CSR fill (counting-sort scatter) ----------------
__global__ void k_fill(const int* __restrict__ ei, const float* __restrict__ dinv,
                       int* __restrict__ cursor, int* __restrict__ col, float* __restrict__ val) {
    int i = blockIdx.x * 256 + threadIdx.x;
    if (i < EE) {
        int s = ei[i];
        int d = ei[EE + i];
        float w = dinv[s] * dinv[d];
        int p = atomicAdd(&cursor[d], 1);
        col[p] = s;
        val[p] = w;
    } else if (i < EE + NN) {
        int n = i - EE;
        float di = dinv[n];
        int p = atomicAdd(&cursor[n], 1);
        col[p] = n;
        val[p] = di * di;
    }
}

// ---------------- dense GEMM: Z[nrows,64] = A[nrows,K] @ W[K,64] ----------------
// 64x64 tile per block, 4x4 register blocking per thread, K staged in 64-chunks.
template <int K>
__global__ __launch_bounds__(256) void k_gemm(const float* __restrict__ A, const float* __restrict__ W,
                                              float* __restrict__ Z, int nrows) {
    constexpr int S = 68;  // LDS stride: bank-spread, 16B-aligned
    __shared__ float wl[64 * 64];
    __shared__ float hl[64 * S];
    const int t = threadIdx.x;
    const int r0 = blockIdx.x * 64;
    const int rg = t >> 4, cg = t & 15;
    float acc[4][4] = {};

    for (int kb = 0; kb < K; kb += 64) {
        // stage W rows kb..kb+63 (contiguous)
        {
            const float4* Wv = (const float4*)(W + kb * 64);
            for (int i = t; i < 1024; i += 256) ((float4*)wl)[i] = Wv[i];
        }
        // stage A tile rows r0..r0+63, cols kb..kb+63
        for (int i = t; i < 1024; i += 256) {
            int row = i >> 4, d4 = i & 15;
            float4 v = {0.f, 0.f, 0.f, 0.f};
            if (r0 + row < nrows) v = *(const float4*)(A + (size_t)(r0 + row) * K + kb + d4 * 4);
            *(float4*)(hl + row * S + d4 * 4) = v;
        }
        __syncthreads();
#pragma unroll 8
        for (int d = 0; d < 64; ++d) {
            float4 w4 = *(const float4*)(wl + d * 64 + cg * 4);
#pragma unroll
            for (int i = 0; i < 4; i++) {
                float h = hl[(rg * 4 + i) * S + d];
                acc[i][0] = fmaf(h, w4.x, acc[i][0]);
                acc[i][1] = fmaf(h, w4.y, acc[i][1]);
                acc[i][2] = fmaf(h, w4.z, acc[i][2]);
                acc[i][3] = fmaf(h, w4.w, acc[i][3]);
            }
        }
        __syncthreads();
    }
#pragma unroll
    for (int i = 0; i < 4; i++) {
        int row = r0 + rg * 4 + i;
        if (row < nrows) {
            float4 o = {acc[i][0], acc[i][1], acc[i][2], acc[i][3]};
            *(float4*)(Z + (size_t)row * 64 + cg * 4) = o;
        }
    }
}

// ---------------- fused q/k GEMMs + row-dot -> scores[4N] ----------------
__global__ __launch_bounds__(256) void k_qkscore(const float* __restrict__ Hm, const float* __restrict__ Wq,
                                                 const float* __restrict__ Wk, float* __restrict__ scores) {
    constexpr int S = 68;
    __shared__ float wq[4096], wk[4096];
    __shared__ float hl[64 * S];
    const int t = threadIdx.x;
    const int r0 = blockIdx.x * 64;  // 4N = 400000 = 6250*64, no tail
    for (int i = t; i < 1024; i += 256) {
        ((float4*)wq)[i] = ((const float4*)Wq)[i];
        ((float4*)wk)[i] = ((const float4*)Wk)[i];
    }
    for (int i = t; i < 1024; i += 256) {
        int row = i >> 4, d4 = i & 15;
        *(float4*)(hl + row * S + d4 * 4) = *(const float4*)(Hm + (size_t)(r0 + row) * 64 + d4 * 4);
    }
    __syncthreads();
    const int rg = t >> 4, cg = t & 15;
    float aq[4][4] = {}, ak[4][4] = {};
#pragma unroll 8
    for (int d = 0; d < 64; ++d) {
        float4 q4 = *(const float4*)(wq + d * 64 + cg * 4);
        float4 k4 = *(const float4*)(wk + d * 64 + cg * 4);
#pragma unroll
        for (int i = 0; i < 4; i++) {
            float h = hl[(rg * 4 + i) * S + d];
            aq[i][0] = fmaf(h, q4.x, aq[i][0]);
            aq[i][1] = fmaf(h, q4.y, aq[i][1]);
            aq[i][2] = fmaf(h, q4.z, aq[i][2]);
            aq[i][3] = fmaf(h, q4.w, aq[i][3]);
            ak[i][0] = fmaf(h, k4.x, ak[i][0]);
            ak[i][1] = fmaf(h, k4.y, ak[i][1]);
            ak[i][2] = fmaf(h, k4.z, ak[i][2]);
            ak[i][3] = fmaf(h, k4.w, ak[i][3]);
        }
    }
#pragma unroll
    for (int i = 0; i < 4; i++) {
        float p = aq[i][0] * ak[i][0] + aq[i][1] * ak[i][1] + aq[i][2] * ak[i][2] + aq[i][3] * ak[i][3];
        p += __shfl_xor(p, 1);
        p += __shfl_xor(p, 2);
        p += __shfl_xor(p, 4);
        p += __shfl_xor(p, 8);
        if (cg == 0) scores[r0 + rg * 4 + i] = p;  // raw q.k (TEMP applied later)
    }
}

// ---------------- propagate: out[n] = relu(sum_e val*z[col] + bias) ----------------
__global__ __launch_bounds__(256) void k_prop(const float* __restrict__ z, const int* __restrict__ rp,
                                              const int* __restrict__ col, const float* __restrict__ val,
                                              const float* __restrict__ bias, float* __restrict__ out) {
    const int lane = threadIdx.x & 63;
    const int n = blockIdx.x * 4 + (threadIdx.x >> 6);  // grid exactly covers N
    const int beg = rp[n], end = rp[n + 1];
    float acc = 0.f;
    for (int i = beg; i < end; ++i) {
        int c = col[i];     // wave-uniform
        float v = val[i];   // wave-uniform
        acc = fmaf(v, z[(size_t)c * 64 + lane], acc);
    }
    float r = acc + bias[lane];
    out[(size_t)n * 64 + lane] = r > 0.f ? r : 0.f;
}

// ---------------- summarize: softmax over layers + hsum + out GEMV ----------------
__global__ __launch_bounds__(256) void k_sum(const float* __restrict__ Hm, const float* __restrict__ scores,
                                             const float* __restrict__ Wout, const float* __restrict__ bout,
                                             float* __restrict__ out) {
    __shared__ float wo[64 * CC];
    const int t = threadIdx.x;
    for (int i = t; i < (64 * CC) / 4; i += 256) ((float4*)wo)[i] = ((const float4*)Wout)[i];
    __syncthreads();
    const int lane = t & 63;
    const int n = blockIdx.x * 4 + (t >> 6);
    float h0 = Hm[(size_t)(0 * NN + n) * 64 + lane];
    float h1 = Hm[(size_t)(1 * NN + n) * 64 + lane];
    float h2 = Hm[(size_t)(2 * NN + n) * 64 + lane];
    float h3 = Hm[(size_t)(3 * NN + n) * 64 + lane];
    float s0 = scores[0 * NN + n] * 10.f;  // 1/TEMP = 10
    float s1 = scores[1 * NN + n] * 10.f;
    float s2 = scores[2 * NN + n] * 10.f;
    float s3 = scores[3 * NN + n] * 10.f;
    float m = fmaxf(fmaxf(s0, s1), fmaxf(s2, s3));
    float e0 = expf(s0 - m), e1 = expf(s1 - m), e2 = expf(s2 - m), e3 = expf(s3 - m);
    float inv = 1.f / (e0 + e1 + e2 + e3);
    float hs = (e0 * h0 + e1 * h1 + e2 * h2 + e3 * h3) * inv;
    float acc = 0.f;
#pragma unroll 8
    for (int d = 0; d < 64; ++d) {
        float hd = __shfl(hs, d);
        if (lane < CC) acc = fmaf(hd, wo[d * CC + lane], acc);
    }
    if (lane < CC) out[(size_t)n * CC + lane] = acc + bout[lane];
}

// ---------------- host ----------------
extern "C" void kernel_launch(void* const* d_in, const int* in_sizes, int n_in,
                              void* d_out, int out_size, void* d_ws, size_t ws_size,
                              hipStream_t stream) {
    const float* x    = (const float*)d_in[0];
    const int*   ei   = (const int*)d_in[1];   // harness passes integer inputs as int32
    const float* W0   = (const float*)d_in[2];
    const float* b0   = (const float*)d_in[3];
    const float* Ws   = (const float*)d_in[4];
    const float* bs   = (const float*)d_in[5];
    const float* Wq   = (const float*)d_in[6];
    const float* Wk   = (const float*)d_in[7];
    const float* Wout = (const float*)d_in[8];
    const float* bout = (const float*)d_in[9];
    float* out = (float*)d_out;

    // workspace carve (256B aligned slabs)
    char* p = (char*)d_ws;
    auto carve = [&](size_t bytes) {
        void* r = (void*)p;
        p += (bytes + 255) & ~(size_t)255;
        return r;
    };
    int*   deg     = (int*)carve((size_t)NN * 4);
    float* dinv    = (float*)carve((size_t)NN * 4);
    int*   row_ptr = (int*)carve((size_t)(NN + 1) * 4);
    int*   cursor  = (int*)carve((size_t)NN * 4);
    int*   bsum    = (int*)carve(256 * 4);
    int*   col     = (int*)carve((size_t)(EE + NN) * 4);
    float* val     = (float*)carve((size_t)(EE + NN) * 4);
    float* z       = (float*)carve((size_t)NN * HH * 4);
    float* Hm      = (float*)carve((size_t)4 * NN * HH * 4);
    float* scores  = (float*)carve((size_t)4 * NN * 4);
    (void)ws_size; (void)n_in; (void)in_sizes; (void)out_size;

    const int GB_N  = (NN + 255) / 256;            // 391
    const int GB_E  = EE / 256;                    // 6250
    const int GB_EN = (EE + NN + 255) / 256;       // 6641
    const int GT    = (NN + 63) / 64;              // 1563 row tiles
    const int GQK   = (4 * NN) / 64;               // 6250
    const int GP    = NN / 4;                      // 25000

    // graph norm + CSR build
    k_init_deg<<<GB_N, 256, 0, stream>>>(deg);
    k_count<<<GB_E, 256, 0, stream>>>(ei, deg);
    k_dinv<<<GB_N, 256, 0, stream>>>(deg, dinv);
    k_scanA<<<NB, SCAN_B, 0, stream>>>(deg, row_ptr, bsum);
    k_scanB<<<1, 128, 0, stream>>>(bsum);
    k_scanC<<<NB, SCAN_B, 0, stream>>>(row_ptr, bsum, cursor);
    k_fill<<<GB_EN, 256, 0, stream>>>(ei, dinv, cursor, col, val);

    // layer 0: z = x @ W0 ; Hm[0] = relu(prop(z) + b0)
    k_gemm<FF><<<GT, 256, 0, stream>>>(x, W0, z, NN);
    k_prop<<<GP, 256, 0, stream>>>(z, row_ptr, col, val, b0, Hm);
    // layers 1..3
    for (int l = 1; l < 4; ++l) {
        k_gemm<HH><<<GT, 256, 0, stream>>>(Hm + (size_t)(l - 1) * NN * HH,
                                           Ws + (size_t)(l - 1) * HH * HH, z, NN);
        k_prop<<<GP, 256, 0, stream>>>(z, row_ptr, col, val, bs + (size_t)(l - 1) * HH,
                                       Hm + (size_t)l * NN * HH);
    }

    // attention scores (q.k fused, no q/k materialization)
    k_qkscore<<<GQK, 256, 0, stream>>>(Hm, Wq, Wk, scores);
    // softmax over layers + weighted sum + output projection
    k_sum<<<GP, 256, 0, stream>>>(Hm, scores, Wout, bout, out);
}

// Round 2
// 916.539 us; speedup vs baseline: 1.2577x; 1.2577x over previous
//
#include <hip/hip_runtime.h>
#include <hip/hip_bf16.h>
#include <math.h>

#define NN 100000
#define EE 1600000
#define FF 128
#define HH 64
#define CC 40

constexpr int SCAN_B = 1024;
constexpr int NB = (NN + SCAN_B - 1) / SCAN_B;  // 98

// ---------------- degree / norm ----------------
__global__ void k_init_deg(int* __restrict__ deg) {
    int i = blockIdx.x * 256 + threadIdx.x;
    if (i < NN) deg[i] = 1;  // self-loop contributes 1
}

__global__ void k_count(const int* __restrict__ ei, int* __restrict__ deg) {
    int e = blockIdx.x * 256 + threadIdx.x;
    if (e < EE) atomicAdd(&deg[ei[EE + e]], 1);
}

__global__ void k_dinv(const int* __restrict__ deg, float* __restrict__ dinv) {
    int i = blockIdx.x * 256 + threadIdx.x;
    if (i < NN) dinv[i] = rsqrtf((float)deg[i]);  // deg >= 1 always
}

// ---------------- exclusive scan (3-kernel) ----------------
__global__ void k_scanA(const int* __restrict__ deg, int* __restrict__ excl, int* __restrict__ bsum) {
    __shared__ int s[SCAN_B];
    int t = threadIdx.x;
    int g = blockIdx.x * SCAN_B + t;
    int v = (g < NN) ? deg[g] : 0;
    s[t] = v;
    __syncthreads();
    for (int o = 1; o < SCAN_B; o <<= 1) {
        int u = (t >= o) ? s[t - o] : 0;
        __syncthreads();
        s[t] += u;
        __syncthreads();
    }
    if (g < NN) excl[g] = s[t] - v;
    if (t == SCAN_B - 1) bsum[blockIdx.x] = s[t];
}

__global__ void k_scanB(int* __restrict__ bsum) {
    __shared__ int s[128];
    int t = threadIdx.x;
    int v = (t < NB) ? bsum[t] : 0;
    s[t] = v;
    __syncthreads();
    for (int o = 1; o < 128; o <<= 1) {
        int u = (t >= o) ? s[t - o] : 0;
        __syncthreads();
        s[t] += u;
        __syncthreads();
    }
    if (t < NB) bsum[t] = s[t] - v;  // exclusive block offsets
}

__global__ void k_scanC(int* __restrict__ rp, const int* __restrict__ bsum, int* __restrict__ cursor) {
    int t = threadIdx.x;
    int g = blockIdx.x * SCAN_B + t;
    if (g < NN) {
        int v = rp[g] + bsum[blockIdx.x];
        rp[g] = v;
        cursor[g] = v;
    }
    if (g == 0) rp[NN] = EE + NN;
}

// ---------------- CSR fill (counting-sort scatter) ----------------
__global__ void k_fill(const int* __restrict__ ei, const float* __restrict__ dinv,
                       int* __restrict__ cursor, int* __restrict__ col, float* __restrict__ val) {
    int i = blockIdx.x * 256 + threadIdx.x;
    if (i < EE) {
        int s = ei[i];
        int d = ei[EE + i];
        float w = dinv[s] * dinv[d];
        int p = atomicAdd(&cursor[d], 1);
        col[p] = s;
        val[p] = w;
    } else if (i < EE + NN) {
        int n = i - EE;
        float di = dinv[n];
        int p = atomicAdd(&cursor[n], 1);
        col[p] = n;
        val[p] = di * di;
    }
}

// ---------------- dense GEMM: Z[nrows,64] = A[nrows,K] @ W[K,64] ----------------
template <int K>
__global__ __launch_bounds__(256) void k_gemm(const float* __restrict__ A, const float* __restrict__ W,
                                              float* __restrict__ Z, int nrows) {
    constexpr int S = 68;  // LDS stride: bank-spread, 16B-aligned
    __shared__ float wl[64 * 64];
    __shared__ float hl[64 * S];
    const int t = threadIdx.x;
    const int r0 = blockIdx.x * 64;
    const int rg = t >> 4, cg = t & 15;
    float acc[4][4] = {};

    for (int kb = 0; kb < K; kb += 64) {
        {
            const float4* Wv = (const float4*)(W + kb * 64);
            for (int i = t; i < 1024; i += 256) ((float4*)wl)[i] = Wv[i];
        }
        for (int i = t; i < 1024; i += 256) {
            int row = i >> 4, d4 = i & 15;
            float4 v = {0.f, 0.f, 0.f, 0.f};
            if (r0 + row < nrows) v = *(const float4*)(A + (size_t)(r0 + row) * K + kb + d4 * 4);
            *(float4*)(hl + row * S + d4 * 4) = v;
        }
        __syncthreads();
#pragma unroll 8
        for (int d = 0; d < 64; ++d) {
            float4 w4 = *(const float4*)(wl + d * 64 + cg * 4);
#pragma unroll
            for (int i = 0; i < 4; i++) {
                float h = hl[(rg * 4 + i) * S + d];
                acc[i][0] = fmaf(h, w4.x, acc[i][0]);
                acc[i][1] = fmaf(h, w4.y, acc[i][1]);
                acc[i][2] = fmaf(h, w4.z, acc[i][2]);
                acc[i][3] = fmaf(h, w4.w, acc[i][3]);
            }
        }
        __syncthreads();
    }
#pragma unroll
    for (int i = 0; i < 4; i++) {
        int row = r0 + rg * 4 + i;
        if (row < nrows) {
            float4 o = {acc[i][0], acc[i][1], acc[i][2], acc[i][3]};
            *(float4*)(Z + (size_t)row * 64 + cg * 4) = o;
        }
    }
}

// ---------------- fused q/k GEMMs + row-dot -> scores[4N] ----------------
__global__ __launch_bounds__(256) void k_qkscore(const float* __restrict__ Hm, const float* __restrict__ Wq,
                                                 const float* __restrict__ Wk, float* __restrict__ scores) {
    constexpr int S = 68;
    __shared__ float wq[4096], wk[4096];
    __shared__ float hl[64 * S];
    const int t = threadIdx.x;
    const int r0 = blockIdx.x * 64;  // 4N = 400000 = 6250*64, no tail
    for (int i = t; i < 1024; i += 256) {
        ((float4*)wq)[i] = ((const float4*)Wq)[i];
        ((float4*)wk)[i] = ((const float4*)Wk)[i];
    }
    for (int i = t; i < 1024; i += 256) {
        int row = i >> 4, d4 = i & 15;
        *(float4*)(hl + row * S + d4 * 4) = *(const float4*)(Hm + (size_t)(r0 + row) * 64 + d4 * 4);
    }
    __syncthreads();
    const int rg = t >> 4, cg = t & 15;
    float aq[4][4] = {}, ak[4][4] = {};
#pragma unroll 8
    for (int d = 0; d < 64; ++d) {
        float4 q4 = *(const float4*)(wq + d * 64 + cg * 4);
        float4 k4 = *(const float4*)(wk + d * 64 + cg * 4);
#pragma unroll
        for (int i = 0; i < 4; i++) {
            float h = hl[(rg * 4 + i) * S + d];
            aq[i][0] = fmaf(h, q4.x, aq[i][0]);
            aq[i][1] = fmaf(h, q4.y, aq[i][1]);
            aq[i][2] = fmaf(h, q4.z, aq[i][2]);
            aq[i][3] = fmaf(h, q4.w, aq[i][3]);
            ak[i][0] = fmaf(h, k4.x, ak[i][0]);
            ak[i][1] = fmaf(h, k4.y, ak[i][1]);
            ak[i][2] = fmaf(h, k4.z, ak[i][2]);
            ak[i][3] = fmaf(h, k4.w, ak[i][3]);
        }
    }
#pragma unroll
    for (int i = 0; i < 4; i++) {
        float p = aq[i][0] * ak[i][0] + aq[i][1] * ak[i][1] + aq[i][2] * ak[i][2] + aq[i][3] * ak[i][3];
        p += __shfl_xor(p, 1);
        p += __shfl_xor(p, 2);
        p += __shfl_xor(p, 4);
        p += __shfl_xor(p, 8);
        if (cg == 0) scores[r0 + rg * 4 + i] = p;  // raw q.k (TEMP applied later)
    }
}

// ---------------- propagate: out[n] = relu(sum_e val*z[col] + bias) ----------------
// Unroll-by-4: 4 independent col->z gather chains in flight per wave (latency fix).
// col/val marked nontemporal: streamed once, keep z resident in L2.
__global__ __launch_bounds__(256) void k_prop(const float* __restrict__ z, const int* __restrict__ rp,
                                              const int* __restrict__ col, const float* __restrict__ val,
                                              const float* __restrict__ bias, float* __restrict__ out) {
    const int lane = threadIdx.x & 63;
    const int n = blockIdx.x * 4 + (threadIdx.x >> 6);  // grid exactly covers N
    const int beg = rp[n], end = rp[n + 1];
    float a0 = 0.f, a1 = 0.f, a2 = 0.f, a3 = 0.f;
    int i = beg;
    for (; i + 4 <= end; i += 4) {
        int c0 = __builtin_nontemporal_load(col + i);
        int c1 = __builtin_nontemporal_load(col + i + 1);
        int c2 = __builtin_nontemporal_load(col + i + 2);
        int c3 = __builtin_nontemporal_load(col + i + 3);
        float v0 = __builtin_nontemporal_load(val + i);
        float v1 = __builtin_nontemporal_load(val + i + 1);
        float v2 = __builtin_nontemporal_load(val + i + 2);
        float v3 = __builtin_nontemporal_load(val + i + 3);
        float z0 = z[(size_t)c0 * 64 + lane];
        float z1 = z[(size_t)c1 * 64 + lane];
        float z2 = z[(size_t)c2 * 64 + lane];
        float z3 = z[(size_t)c3 * 64 + lane];
        a0 = fmaf(v0, z0, a0);
        a1 = fmaf(v1, z1, a1);
        a2 = fmaf(v2, z2, a2);
        a3 = fmaf(v3, z3, a3);
    }
    for (; i < end; ++i) {
        int c = __builtin_nontemporal_load(col + i);
        float v = __builtin_nontemporal_load(val + i);
        a0 = fmaf(v, z[(size_t)c * 64 + lane], a0);
    }
    float r = (a0 + a1) + (a2 + a3) + bias[lane];
    out[(size_t)n * 64 + lane] = r > 0.f ? r : 0.f;
}

// ---------------- summarize: softmax over layers + hsum + out GEMV ----------------
__global__ __launch_bounds__(256) void k_sum(const float* __restrict__ Hm, const float* __restrict__ scores,
                                             const float* __restrict__ Wout, const float* __restrict__ bout,
                                             float* __restrict__ out) {
    __shared__ float wo[64 * CC];
    const int t = threadIdx.x;
    for (int i = t; i < (64 * CC) / 4; i += 256) ((float4*)wo)[i] = ((const float4*)Wout)[i];
    __syncthreads();
    const int lane = t & 63;
    const int n = blockIdx.x * 4 + (t >> 6);
    float h0 = Hm[(size_t)(0 * NN + n) * 64 + lane];
    float h1 = Hm[(size_t)(1 * NN + n) * 64 + lane];
    float h2 = Hm[(size_t)(2 * NN + n) * 64 + lane];
    float h3 = Hm[(size_t)(3 * NN + n) * 64 + lane];
    float s0 = scores[0 * NN + n] * 10.f;  // 1/TEMP = 10
    float s1 = scores[1 * NN + n] * 10.f;
    float s2 = scores[2 * NN + n] * 10.f;
    float s3 = scores[3 * NN + n] * 10.f;
    float m = fmaxf(fmaxf(s0, s1), fmaxf(s2, s3));
    float e0 = expf(s0 - m), e1 = expf(s1 - m), e2 = expf(s2 - m), e3 = expf(s3 - m);
    float inv = 1.f / (e0 + e1 + e2 + e3);
    float hs = (e0 * h0 + e1 * h1 + e2 * h2 + e3 * h3) * inv;
    float acc = 0.f;
#pragma unroll 8
    for (int d = 0; d < 64; ++d) {
        float hd = __shfl(hs, d);
        if (lane < CC) acc = fmaf(hd, wo[d * CC + lane], acc);
    }
    if (lane < CC) out[(size_t)n * CC + lane] = acc + bout[lane];
}

// ---------------- host ----------------
extern "C" void kernel_launch(void* const* d_in, const int* in_sizes, int n_in,
                              void* d_out, int out_size, void* d_ws, size_t ws_size,
                              hipStream_t stream) {
    const float* x    = (const float*)d_in[0];
    const int*   ei   = (const int*)d_in[1];
    const float* W0   = (const float*)d_in[2];
    const float* b0   = (const float*)d_in[3];
    const float* Ws   = (const float*)d_in[4];
    const float* bs   = (const float*)d_in[5];
    const float* Wq   = (const float*)d_in[6];
    const float* Wk   = (const float*)d_in[7];
    const float* Wout = (const float*)d_in[8];
    const float* bout = (const float*)d_in[9];
    float* out = (float*)d_out;

    char* p = (char*)d_ws;
    auto carve = [&](size_t bytes) {
        void* r = (void*)p;
        p += (bytes + 255) & ~(size_t)255;
        return r;
    };
    int*   deg     = (int*)carve((size_t)NN * 4);
    float* dinv    = (float*)carve((size_t)NN * 4);
    int*   row_ptr = (int*)carve((size_t)(NN + 1) * 4);
    int*   cursor  = (int*)carve((size_t)NN * 4);
    int*   bsum    = (int*)carve(256 * 4);
    int*   col     = (int*)carve((size_t)(EE + NN) * 4);
    float* val     = (float*)carve((size_t)(EE + NN) * 4);
    float* z       = (float*)carve((size_t)NN * HH * 4);
    float* Hm      = (float*)carve((size_t)4 * NN * HH * 4);
    float* scores  = (float*)carve((size_t)4 * NN * 4);
    (void)ws_size; (void)n_in; (void)in_sizes; (void)out_size;

    const int GB_N  = (NN + 255) / 256;
    const int GB_E  = EE / 256;
    const int GB_EN = (EE + NN + 255) / 256;
    const int GT    = (NN + 63) / 64;
    const int GQK   = (4 * NN) / 64;
    const int GP    = NN / 4;

    k_init_deg<<<GB_N, 256, 0, stream>>>(deg);
    k_count<<<GB_E, 256, 0, stream>>>(ei, deg);
    k_dinv<<<GB_N, 256, 0, stream>>>(deg, dinv);
    k_scanA<<<NB, SCAN_B, 0, stream>>>(deg, row_ptr, bsum);
    k_scanB<<<1, 128, 0, stream>>>(bsum);
    k_scanC<<<NB, SCAN_B, 0, stream>>>(row_ptr, bsum, cursor);
    k_fill<<<GB_EN, 256, 0, stream>>>(ei, dinv, cursor, col, val);

    k_gemm<FF><<<GT, 256, 0, stream>>>(x, W0, z, NN);
    k_prop<<<GP, 256, 0, stream>>>(z, row_ptr, col, val, b0, Hm);
    for (int l = 1; l < 4; ++l) {
        k_gemm<HH><<<GT, 256, 0, stream>>>(Hm + (size_t)(l - 1) * NN * HH,
                                           Ws + (size_t)(l - 1) * HH * HH, z, NN);
        k_prop<<<GP, 256, 0, stream>>>(z, row_ptr, col, val, bs + (size_t)(l - 1) * HH,
                                       Hm + (size_t)l * NN * HH);
    }

    k_qkscore<<<GQK, 256, 0, stream>>>(Hm, Wq, Wk, scores);
    k_sum<<<GP, 256, 0, stream>>>(Hm, scores, Wout, bout, out);
}

// Round 4
// 768.498 us; speedup vs baseline: 1.5000x; 1.1926x over previous
//
#include <hip/hip_runtime.h>
#include <hip/hip_bf16.h>
#include <math.h>

#define NN 100000
#define EE 1600000
#define FF 128
#define HH 64
#define CC 40

constexpr int SCAN_B = 1024;
constexpr int NB = (NN + SCAN_B - 1) / SCAN_B;  // 98

typedef unsigned long long u64;

__device__ __forceinline__ u64 pack_cv(int c, float v) {
    return (u64)(unsigned)c | ((u64)(unsigned)__float_as_int(v) << 32);
}
__device__ __forceinline__ int cv_col(u64 u) { return (int)(unsigned)u; }
__device__ __forceinline__ float cv_val(u64 u) { return __int_as_float((int)(u >> 32)); }

// ---------------- degree / norm ----------------
__global__ void k_init_deg(int* __restrict__ deg) {
    int i = blockIdx.x * 256 + threadIdx.x;
    if (i < NN) deg[i] = 1;  // self-loop contributes 1
}

__global__ void k_count(const int* __restrict__ ei, int* __restrict__ deg) {
    int e = blockIdx.x * 256 + threadIdx.x;
    if (e < EE) atomicAdd(&deg[ei[EE + e]], 1);
}

__global__ void k_dinv(const int* __restrict__ deg, float* __restrict__ dinv) {
    int i = blockIdx.x * 256 + threadIdx.x;
    if (i < NN) dinv[i] = rsqrtf((float)deg[i]);  // deg >= 1 always
}

// ---------------- exclusive scan (3-kernel) ----------------
__global__ void k_scanA(const int* __restrict__ deg, int* __restrict__ excl, int* __restrict__ bsum) {
    __shared__ int s[SCAN_B];
    int t = threadIdx.x;
    int g = blockIdx.x * SCAN_B + t;
    int v = (g < NN) ? deg[g] : 0;
    s[t] = v;
    __syncthreads();
    for (int o = 1; o < SCAN_B; o <<= 1) {
        int u = (t >= o) ? s[t - o] : 0;
        __syncthreads();
        s[t] += u;
        __syncthreads();
    }
    if (g < NN) excl[g] = s[t] - v;
    if (t == SCAN_B - 1) bsum[blockIdx.x] = s[t];
}

__global__ void k_scanB(int* __restrict__ bsum) {
    __shared__ int s[128];
    int t = threadIdx.x;
    int v = (t < NB) ? bsum[t] : 0;
    s[t] = v;
    __syncthreads();
    for (int o = 1; o < 128; o <<= 1) {
        int u = (t >= o) ? s[t - o] : 0;
        __syncthreads();
        s[t] += u;
        __syncthreads();
    }
    if (t < NB) bsum[t] = s[t] - v;  // exclusive block offsets
}

__global__ void k_scanC(int* __restrict__ rp, const int* __restrict__ bsum, int* __restrict__ cursor) {
    int t = threadIdx.x;
    int g = blockIdx.x * SCAN_B + t;
    if (g < NN) {
        int v = rp[g] + bsum[blockIdx.x];
        rp[g] = v;
        cursor[g] = v;
    }
    if (g == 0) rp[NN] = EE + NN;
}

// ---------------- CSR fill: single 8B scatter per edge {col, val} ----------------
__global__ void k_fill(const int* __restrict__ ei, const float* __restrict__ dinv,
                       int* __restrict__ cursor, u64* __restrict__ cv) {
    int i = blockIdx.x * 256 + threadIdx.x;
    if (i < EE) {
        int s = ei[i];
        int d = ei[EE + i];
        float w = dinv[s] * dinv[d];
        int p = atomicAdd(&cursor[d], 1);
        __builtin_nontemporal_store(pack_cv(s, w), cv + p);
    } else if (i < EE + NN) {
        int n = i - EE;
        float di = dinv[n];
        int p = atomicAdd(&cursor[n], 1);
        __builtin_nontemporal_store(pack_cv(n, di * di), cv + p);
    }
}

// ---------------- dense GEMM: Z[nrows,64] = A[nrows,K] @ W[K,64] ----------------
template <int K>
__global__ __launch_bounds__(256) void k_gemm(const float* __restrict__ A, const float* __restrict__ W,
                                              float* __restrict__ Z, int nrows) {
    constexpr int S = 68;  // LDS stride: bank-spread, 16B-aligned
    __shared__ float wl[64 * 64];
    __shared__ float hl[64 * S];
    const int t = threadIdx.x;
    const int r0 = blockIdx.x * 64;
    const int rg = t >> 4, cg = t & 15;
    float acc[4][4] = {};

    for (int kb = 0; kb < K; kb += 64) {
        {
            const float4* Wv = (const float4*)(W + kb * 64);
            for (int i = t; i < 1024; i += 256) ((float4*)wl)[i] = Wv[i];
        }
        for (int i = t; i < 1024; i += 256) {
            int row = i >> 4, d4 = i & 15;
            float4 v = {0.f, 0.f, 0.f, 0.f};
            if (r0 + row < nrows) v = *(const float4*)(A + (size_t)(r0 + row) * K + kb + d4 * 4);
            *(float4*)(hl + row * S + d4 * 4) = v;
        }
        __syncthreads();
#pragma unroll 8
        for (int d = 0; d < 64; ++d) {
            float4 w4 = *(const float4*)(wl + d * 64 + cg * 4);
#pragma unroll
            for (int i = 0; i < 4; i++) {
                float h = hl[(rg * 4 + i) * S + d];
                acc[i][0] = fmaf(h, w4.x, acc[i][0]);
                acc[i][1] = fmaf(h, w4.y, acc[i][1]);
                acc[i][2] = fmaf(h, w4.z, acc[i][2]);
                acc[i][3] = fmaf(h, w4.w, acc[i][3]);
            }
        }
        __syncthreads();
    }
#pragma unroll
    for (int i = 0; i < 4; i++) {
        int row = r0 + rg * 4 + i;
        if (row < nrows) {
            float4 o = {acc[i][0], acc[i][1], acc[i][2], acc[i][3]};
            *(float4*)(Z + (size_t)row * 64 + cg * 4) = o;
        }
    }
}

// ---------------- fused q/k GEMMs + row-dot -> scores[4N] ----------------
__global__ __launch_bounds__(256) void k_qkscore(const float* __restrict__ Hm, const float* __restrict__ Wq,
                                                 const float* __restrict__ Wk, float* __restrict__ scores) {
    constexpr int S = 68;
    __shared__ float wq[4096], wk[4096];
    __shared__ float hl[64 * S];
    const int t = threadIdx.x;
    const int r0 = blockIdx.x * 64;  // 4N = 400000 = 6250*64, no tail
    for (int i = t; i < 1024; i += 256) {
        ((float4*)wq)[i] = ((const float4*)Wq)[i];
        ((float4*)wk)[i] = ((const float4*)Wk)[i];
    }
    for (int i = t; i < 1024; i += 256) {
        int row = i >> 4, d4 = i & 15;
        *(float4*)(hl + row * S + d4 * 4) = *(const float4*)(Hm + (size_t)(r0 + row) * 64 + d4 * 4);
    }
    __syncthreads();
    const int rg = t >> 4, cg = t & 15;
    float aq[4][4] = {}, ak[4][4] = {};
#pragma unroll 8
    for (int d = 0; d < 64; ++d) {
        float4 q4 = *(const float4*)(wq + d * 64 + cg * 4);
        float4 k4 = *(const float4*)(wk + d * 64 + cg * 4);
#pragma unroll
        for (int i = 0; i < 4; i++) {
            float h = hl[(rg * 4 + i) * S + d];
            aq[i][0] = fmaf(h, q4.x, aq[i][0]);
            aq[i][1] = fmaf(h, q4.y, aq[i][1]);
            aq[i][2] = fmaf(h, q4.z, aq[i][2]);
            aq[i][3] = fmaf(h, q4.w, aq[i][3]);
            ak[i][0] = fmaf(h, k4.x, ak[i][0]);
            ak[i][1] = fmaf(h, k4.y, ak[i][1]);
            ak[i][2] = fmaf(h, k4.z, ak[i][2]);
            ak[i][3] = fmaf(h, k4.w, ak[i][3]);
        }
    }
#pragma unroll
    for (int i = 0; i < 4; i++) {
        float p = aq[i][0] * ak[i][0] + aq[i][1] * ak[i][1] + aq[i][2] * ak[i][2] + aq[i][3] * ak[i][3];
        p += __shfl_xor(p, 1);
        p += __shfl_xor(p, 2);
        p += __shfl_xor(p, 4);
        p += __shfl_xor(p, 8);
        if (cg == 0) scores[r0 + rg * 4 + i] = p;  // raw q.k (TEMP applied later)
    }
}

// ---------------- propagate: out[n] = relu(sum_e val*z[col] + bias) ----------------
// 16 lanes per node (float4 per lane), 4 nodes per wave, 4 unrolled gather chains
// per node -> up to 16 independent 256B row-gathers in flight per wave.
__global__ __launch_bounds__(256) void k_prop(const float* __restrict__ z, const int* __restrict__ rp,
                                              const u64* __restrict__ cv,
                                              const float* __restrict__ bias, float* __restrict__ out) {
    const int lane = threadIdx.x & 63;
    const int g = lane >> 4;    // node group within wave (0..3)
    const int l4 = lane & 15;   // float4 slot within row
    const int n = blockIdx.x * 16 + (threadIdx.x >> 6) * 4 + g;  // grid covers N exactly
    const int beg = rp[n], end = rp[n + 1];
    float4 a0 = {0, 0, 0, 0}, a1 = {0, 0, 0, 0}, a2 = {0, 0, 0, 0}, a3 = {0, 0, 0, 0};
    int i = beg;
    for (; i + 4 <= end; i += 4) {
        u64 u0 = __builtin_nontemporal_load(cv + i);
        u64 u1 = __builtin_nontemporal_load(cv + i + 1);
        u64 u2 = __builtin_nontemporal_load(cv + i + 2);
        u64 u3 = __builtin_nontemporal_load(cv + i + 3);
        float4 z0 = *(const float4*)(z + (size_t)(unsigned)cv_col(u0) * 64 + l4 * 4);
        float4 z1 = *(const float4*)(z + (size_t)(unsigned)cv_col(u1) * 64 + l4 * 4);
        float4 z2 = *(const float4*)(z + (size_t)(unsigned)cv_col(u2) * 64 + l4 * 4);
        float4 z3 = *(const float4*)(z + (size_t)(unsigned)cv_col(u3) * 64 + l4 * 4);
        float v0 = cv_val(u0), v1 = cv_val(u1), v2 = cv_val(u2), v3 = cv_val(u3);
        a0.x = fmaf(v0, z0.x, a0.x); a0.y = fmaf(v0, z0.y, a0.y);
        a0.z = fmaf(v0, z0.z, a0.z); a0.w = fmaf(v0, z0.w, a0.w);
        a1.x = fmaf(v1, z1.x, a1.x); a1.y = fmaf(v1, z1.y, a1.y);
        a1.z = fmaf(v1, z1.z, a1.z); a1.w = fmaf(v1, z1.w, a1.w);
        a2.x = fmaf(v2, z2.x, a2.x); a2.y = fmaf(v2, z2.y, a2.y);
        a2.z = fmaf(v2, z2.z, a2.z); a2.w = fmaf(v2, z2.w, a2.w);
        a3.x = fmaf(v3, z3.x, a3.x); a3.y = fmaf(v3, z3.y, a3.y);
        a3.z = fmaf(v3, z3.z, a3.z); a3.w = fmaf(v3, z3.w, a3.w);
    }
    for (; i < end; ++i) {
        u64 u = __builtin_nontemporal_load(cv + i);
        float v = cv_val(u);
        float4 zr = *(const float4*)(z + (size_t)(unsigned)cv_col(u) * 64 + l4 * 4);
        a0.x = fmaf(v, zr.x, a0.x); a0.y = fmaf(v, zr.y, a0.y);
        a0.z = fmaf(v, zr.z, a0.z); a0.w = fmaf(v, zr.w, a0.w);
    }
    const float4 b4 = *(const float4*)(bias + l4 * 4);
    float4 r;
    r.x = (a0.x + a1.x) + (a2.x + a3.x) + b4.x;
    r.y = (a0.y + a1.y) + (a2.y + a3.y) + b4.y;
    r.z = (a0.z + a1.z) + (a2.z + a3.z) + b4.z;
    r.w = (a0.w + a1.w) + (a2.w + a3.w) + b4.w;
    r.x = r.x > 0.f ? r.x : 0.f;
    r.y = r.y > 0.f ? r.y : 0.f;
    r.z = r.z > 0.f ? r.z : 0.f;
    r.w = r.w > 0.f ? r.w : 0.f;
    *(float4*)(out + (size_t)n * 64 + l4 * 4) = r;
}

// ---------------- summarize: softmax over layers + hsum + out GEMV ----------------
// hs broadcast via LDS (not shfl: 64-deep ds_bpermute chain was the R2 bottleneck).
__global__ __launch_bounds__(256) void k_sum(const float* __restrict__ Hm, const float* __restrict__ scores,
                                             const float* __restrict__ Wout, const float* __restrict__ bout,
                                             float* __restrict__ out) {
    __shared__ float wo[64 * CC];
    __shared__ float hsl[4][64];
    const int t = threadIdx.x;
    for (int i = t; i < (64 * CC) / 4; i += 256) ((float4*)wo)[i] = ((const float4*)Wout)[i];
    __syncthreads();
    const int lane = t & 63;
    const int wid = t >> 6;
    const int n = blockIdx.x * 4 + wid;
    float h0 = Hm[(size_t)(0 * NN + n) * 64 + lane];
    float h1 = Hm[(size_t)(1 * NN + n) * 64 + lane];
    float h2 = Hm[(size_t)(2 * NN + n) * 64 + lane];
    float h3 = Hm[(size_t)(3 * NN + n) * 64 + lane];
    float s0 = scores[0 * NN + n] * 10.f;  // 1/TEMP = 10
    float s1 = scores[1 * NN + n] * 10.f;
    float s2 = scores[2 * NN + n] * 10.f;
    float s3 = scores[3 * NN + n] * 10.f;
    float m = fmaxf(fmaxf(s0, s1), fmaxf(s2, s3));
    float e0 = __expf(s0 - m), e1 = __expf(s1 - m), e2 = __expf(s2 - m), e3 = __expf(s3 - m);
    float inv = 1.f / (e0 + e1 + e2 + e3);
    float hs = (e0 * h0 + e1 * h1 + e2 * h2 + e3 * h3) * inv;
    hsl[wid][lane] = hs;  // wave-synchronous: written and read by the same wave
    float acc = 0.f;
#pragma unroll 8
    for (int d = 0; d < 64; ++d) {
        if (lane < CC) acc = fmaf(hsl[wid][d], wo[d * CC + lane], acc);
    }
    if (lane < CC) out[(size_t)n * CC + lane] = acc + bout[lane];
}

// ---------------- host ----------------
extern "C" void kernel_launch(void* const* d_in, const int* in_sizes, int n_in,
                              void* d_out, int out_size, void* d_ws, size_t ws_size,
                              hipStream_t stream) {
    const float* x    = (const float*)d_in[0];
    const int*   ei   = (const int*)d_in[1];
    const float* W0   = (const float*)d_in[2];
    const float* b0   = (const float*)d_in[3];
    const float* Ws   = (const float*)d_in[4];
    const float* bs   = (const float*)d_in[5];
    const float* Wq   = (const float*)d_in[6];
    const float* Wk   = (const float*)d_in[7];
    const float* Wout = (const float*)d_in[8];
    const float* bout = (const float*)d_in[9];
    float* out = (float*)d_out;

    char* p = (char*)d_ws;
    auto carve = [&](size_t bytes) {
        void* r = (void*)p;
        p += (bytes + 255) & ~(size_t)255;
        return r;
    };
    int*   deg     = (int*)carve((size_t)NN * 4);
    float* dinv    = (float*)carve((size_t)NN * 4);
    int*   row_ptr = (int*)carve((size_t)(NN + 1) * 4);
    int*   cursor  = (int*)carve((size_t)NN * 4);
    int*   bsum    = (int*)carve(256 * 4);
    u64*   cv      = (u64*)carve((size_t)(EE + NN) * 8);
    float* z       = (float*)carve((size_t)NN * HH * 4);
    float* Hm      = (float*)carve((size_t)4 * NN * HH * 4);
    float* scores  = (float*)carve((size_t)4 * NN * 4);
    (void)ws_size; (void)n_in; (void)in_sizes; (void)out_size;

    const int GB_N  = (NN + 255) / 256;
    const int GB_E  = EE / 256;
    const int GB_EN = (EE + NN + 255) / 256;
    const int GT    = (NN + 63) / 64;
    const int GQK   = (4 * NN) / 64;
    const int GP    = NN / 16;   // 6250: 16 nodes per block (4/wave)
    const int GS    = NN / 4;    // 25000

    k_init_deg<<<GB_N, 256, 0, stream>>>(deg);
    k_count<<<GB_E, 256, 0, stream>>>(ei, deg);
    k_dinv<<<GB_N, 256, 0, stream>>>(deg, dinv);
    k_scanA<<<NB, SCAN_B, 0, stream>>>(deg, row_ptr, bsum);
    k_scanB<<<1, 128, 0, stream>>>(bsum);
    k_scanC<<<NB, SCAN_B, 0, stream>>>(row_ptr, bsum, cursor);
    k_fill<<<GB_EN, 256, 0, stream>>>(ei, dinv, cursor, cv);

    k_gemm<FF><<<GT, 256, 0, stream>>>(x, W0, z, NN);
    k_prop<<<GP, 256, 0, stream>>>(z, row_ptr, cv, b0, Hm);
    for (int l = 1; l < 4; ++l) {
        k_gemm<HH><<<GT, 256, 0, stream>>>(Hm + (size_t)(l - 1) * NN * HH,
                                           Ws + (size_t)(l - 1) * HH * HH, z, NN);
        k_prop<<<GP, 256, 0, stream>>>(z, row_ptr, cv, bs + (size_t)(l - 1) * HH,
                                       Hm + (size_t)l * NN * HH);
    }

    k_qkscore<<<GQK, 256, 0, stream>>>(Hm, Wq, Wk, scores);
    k_sum<<<GS, 256, 0, stream>>>(Hm, scores, Wout, bout, out);
}

// Round 5
// 761.577 us; speedup vs baseline: 1.5136x; 1.0091x over previous
//
#include <hip/hip_runtime.h>
#include <hip/hip_bf16.h>
#include <math.h>

#define NN 100000
#define EE 1600000
#define FF 128
#define HH 64
#define CC 40

constexpr int SCAN_B = 1024;
constexpr int NB = (NN + SCAN_B - 1) / SCAN_B;  // 98

// ---------------- degree / norm ----------------
__global__ void k_init_deg(int* __restrict__ deg) {
    int i = blockIdx.x * 256 + threadIdx.x;
    if (i < NN) deg[i] = 1;  // self-loop contributes 1
}

// int4-vectorized dst counting (4 edges/thread)
__global__ void k_count(const int* __restrict__ ei, int* __restrict__ deg) {
    int i = blockIdx.x * 256 + threadIdx.x;
    if (i < EE / 4) {
        int4 d = ((const int4*)(ei + EE))[i];
        atomicAdd(&deg[d.x], 1);
        atomicAdd(&deg[d.y], 1);
        atomicAdd(&deg[d.z], 1);
        atomicAdd(&deg[d.w], 1);
    }
}

__global__ void k_dinv(const int* __restrict__ deg, float* __restrict__ dinv) {
    int i = blockIdx.x * 256 + threadIdx.x;
    if (i < NN) dinv[i] = rsqrtf((float)deg[i]);  // deg >= 1 always
}

// ---------------- exclusive scan (3-kernel) ----------------
__global__ void k_scanA(const int* __restrict__ deg, int* __restrict__ excl, int* __restrict__ bsum) {
    __shared__ int s[SCAN_B];
    int t = threadIdx.x;
    int g = blockIdx.x * SCAN_B + t;
    int v = (g < NN) ? deg[g] : 0;
    s[t] = v;
    __syncthreads();
    for (int o = 1; o < SCAN_B; o <<= 1) {
        int u = (t >= o) ? s[t - o] : 0;
        __syncthreads();
        s[t] += u;
        __syncthreads();
    }
    if (g < NN) excl[g] = s[t] - v;
    if (t == SCAN_B - 1) bsum[blockIdx.x] = s[t];
}

__global__ void k_scanB(int* __restrict__ bsum) {
    __shared__ int s[128];
    int t = threadIdx.x;
    int v = (t < NB) ? bsum[t] : 0;
    s[t] = v;
    __syncthreads();
    for (int o = 1; o < 128; o <<= 1) {
        int u = (t >= o) ? s[t - o] : 0;
        __syncthreads();
        s[t] += u;
        __syncthreads();
    }
    if (t < NB) bsum[t] = s[t] - v;  // exclusive block offsets
}

__global__ void k_scanC(int* __restrict__ rp, const int* __restrict__ bsum, int* __restrict__ cursor) {
    int t = threadIdx.x;
    int g = blockIdx.x * SCAN_B + t;
    if (g < NN) {
        int v = rp[g] + bsum[blockIdx.x];
        rp[g] = v;
        cursor[g] = v;
    }
    if (g == 0) rp[NN] = EE + NN;
}

// ---------------- CSR fill: col-only (4B per edge), 4 edges/thread ----------------
__global__ void k_fill(const int* __restrict__ ei, int* __restrict__ cursor, int* __restrict__ cs) {
    int i = blockIdx.x * 256 + threadIdx.x;
    if (i < EE / 4) {
        int4 s4 = ((const int4*)ei)[i];
        int4 d4 = ((const int4*)(ei + EE))[i];
        int p0 = atomicAdd(&cursor[d4.x], 1);
        __builtin_nontemporal_store(s4.x, cs + p0);
        int p1 = atomicAdd(&cursor[d4.y], 1);
        __builtin_nontemporal_store(s4.y, cs + p1);
        int p2 = atomicAdd(&cursor[d4.z], 1);
        __builtin_nontemporal_store(s4.z, cs + p2);
        int p3 = atomicAdd(&cursor[d4.w], 1);
        __builtin_nontemporal_store(s4.w, cs + p3);
    } else if (i < EE / 4 + NN) {
        int n = i - EE / 4;  // self-loop: weight folds into dinv scaling like any edge
        int p = atomicAdd(&cursor[n], 1);
        __builtin_nontemporal_store(n, cs + p);
    }
}

// ---------------- dense GEMM: Z[r,:] = dinv[r] * (A[r,:] @ W)  ----------------
template <int K>
__global__ __launch_bounds__(256) void k_gemm(const float* __restrict__ A, const float* __restrict__ W,
                                              const float* __restrict__ dinv, float* __restrict__ Z,
                                              int nrows) {
    constexpr int S = 68;  // LDS stride: bank-spread, 16B-aligned
    __shared__ float wl[64 * 64];
    __shared__ float hl[64 * S];
    const int t = threadIdx.x;
    const int r0 = blockIdx.x * 64;
    const int rg = t >> 4, cg = t & 15;
    float acc[4][4] = {};

    for (int kb = 0; kb < K; kb += 64) {
        {
            const float4* Wv = (const float4*)(W + kb * 64);
            for (int i = t; i < 1024; i += 256) ((float4*)wl)[i] = Wv[i];
        }
        for (int i = t; i < 1024; i += 256) {
            int row = i >> 4, d4 = i & 15;
            float4 v = {0.f, 0.f, 0.f, 0.f};
            if (r0 + row < nrows) v = *(const float4*)(A + (size_t)(r0 + row) * K + kb + d4 * 4);
            *(float4*)(hl + row * S + d4 * 4) = v;
        }
        __syncthreads();
#pragma unroll 8
        for (int d = 0; d < 64; ++d) {
            float4 w4 = *(const float4*)(wl + d * 64 + cg * 4);
#pragma unroll
            for (int i = 0; i < 4; i++) {
                float h = hl[(rg * 4 + i) * S + d];
                acc[i][0] = fmaf(h, w4.x, acc[i][0]);
                acc[i][1] = fmaf(h, w4.y, acc[i][1]);
                acc[i][2] = fmaf(h, w4.z, acc[i][2]);
                acc[i][3] = fmaf(h, w4.w, acc[i][3]);
            }
        }
        __syncthreads();
    }
#pragma unroll
    for (int i = 0; i < 4; i++) {
        int row = r0 + rg * 4 + i;
        if (row < nrows) {
            float dv = dinv[row];
            float4 o = {acc[i][0] * dv, acc[i][1] * dv, acc[i][2] * dv, acc[i][3] * dv};
            *(float4*)(Z + (size_t)row * 64 + cg * 4) = o;
        }
    }
}

// ---------------- M = Wq @ Wk^T (64x64), 16 blocks x 4 rows ----------------
__global__ __launch_bounds__(256) void k_prepM(const float* __restrict__ Wq, const float* __restrict__ Wk,
                                               float* __restrict__ M) {
    __shared__ float wk[64 * 65];
    __shared__ float wq[4 * 64];
    const int t = threadIdx.x;
    for (int i = t; i < 1024; i += 256) {
        int r = i >> 4, c4 = i & 15;
        float4 v = ((const float4*)Wk)[i];
        wk[r * 65 + c4 * 4 + 0] = v.x;
        wk[r * 65 + c4 * 4 + 1] = v.y;
        wk[r * 65 + c4 * 4 + 2] = v.z;
        wk[r * 65 + c4 * 4 + 3] = v.w;
    }
    const int rbase = blockIdx.x * 4;
    wq[t] = Wq[rbase * 64 + t];
    __syncthreads();
    const int rr = t >> 6;  // 0..3
    const int c = t & 63;
    float acc = 0.f;
#pragma unroll 8
    for (int e = 0; e < 64; ++e) acc = fmaf(wq[rr * 64 + e], wk[c * 65 + e], acc);
    M[(rbase + rr) * 64 + c] = acc;  // M[d][d'] = dot(Wq row d, Wk row d')
}

// ---------------- scores[r] = h_r @ M @ h_r^T (one GEMM + fused dot) ----------------
__global__ __launch_bounds__(256) void k_score(const float* __restrict__ Hm, const float* __restrict__ M,
                                               float* __restrict__ scores) {
    constexpr int S = 68;
    __shared__ float wl[4096];
    __shared__ float hl[64 * S];
    const int t = threadIdx.x;
    const int r0 = blockIdx.x * 64;  // 4N = 400000 = 6250*64, no tail
    for (int i = t; i < 1024; i += 256) ((float4*)wl)[i] = ((const float4*)M)[i];
    for (int i = t; i < 1024; i += 256) {
        int row = i >> 4, d4 = i & 15;
        *(float4*)(hl + row * S + d4 * 4) = *(const float4*)(Hm + (size_t)(r0 + row) * 64 + d4 * 4);
    }
    __syncthreads();
    const int rg = t >> 4, cg = t & 15;
    float u[4][4] = {};
#pragma unroll 8
    for (int d = 0; d < 64; ++d) {
        float4 m4 = *(const float4*)(wl + d * 64 + cg * 4);
#pragma unroll
        for (int i = 0; i < 4; i++) {
            float h = hl[(rg * 4 + i) * S + d];
            u[i][0] = fmaf(h, m4.x, u[i][0]);
            u[i][1] = fmaf(h, m4.y, u[i][1]);
            u[i][2] = fmaf(h, m4.z, u[i][2]);
            u[i][3] = fmaf(h, m4.w, u[i][3]);
        }
    }
#pragma unroll
    for (int i = 0; i < 4; i++) {
        const float* hrow = hl + (rg * 4 + i) * S + cg * 4;
        float p = u[i][0] * hrow[0] + u[i][1] * hrow[1] + u[i][2] * hrow[2] + u[i][3] * hrow[3];
        p += __shfl_xor(p, 1);
        p += __shfl_xor(p, 2);
        p += __shfl_xor(p, 4);
        p += __shfl_xor(p, 8);
        if (cg == 0) scores[r0 + rg * 4 + i] = p;  // raw q.k (TEMP applied later)
    }
}

// ---------------- propagate: out[n] = relu(dinv[n]*sum_e z'[col] + bias) ----------------
// z' is pre-scaled by dinv[src] in the gemm epilogue -> pure gather-sum here.
// 16 lanes/node (float4), 4 nodes/wave, unroll-8 -> 32 row-gathers in flight/wave.
__global__ __launch_bounds__(256) void k_prop(const float* __restrict__ z, const int* __restrict__ rp,
                                              const int* __restrict__ cs, const float* __restrict__ dinv,
                                              const float* __restrict__ bias, float* __restrict__ out) {
    const int lane = threadIdx.x & 63;
    const int g = lane >> 4;    // node group within wave (0..3)
    const int l4 = lane & 15;   // float4 slot within row
    const int n = blockIdx.x * 16 + (threadIdx.x >> 6) * 4 + g;  // grid covers N exactly
    const int beg = rp[n], end = rp[n + 1];
    float4 a0 = {0, 0, 0, 0}, a1 = {0, 0, 0, 0}, a2 = {0, 0, 0, 0}, a3 = {0, 0, 0, 0};
    int i = beg;
    for (; i + 8 <= end; i += 8) {
        int c0 = __builtin_nontemporal_load(cs + i);
        int c1 = __builtin_nontemporal_load(cs + i + 1);
        int c2 = __builtin_nontemporal_load(cs + i + 2);
        int c3 = __builtin_nontemporal_load(cs + i + 3);
        int c4 = __builtin_nontemporal_load(cs + i + 4);
        int c5 = __builtin_nontemporal_load(cs + i + 5);
        int c6 = __builtin_nontemporal_load(cs + i + 6);
        int c7 = __builtin_nontemporal_load(cs + i + 7);
        float4 z0 = *(const float4*)(z + (size_t)(unsigned)c0 * 64 + l4 * 4);
        float4 z1 = *(const float4*)(z + (size_t)(unsigned)c1 * 64 + l4 * 4);
        float4 z2 = *(const float4*)(z + (size_t)(unsigned)c2 * 64 + l4 * 4);
        float4 z3 = *(const float4*)(z + (size_t)(unsigned)c3 * 64 + l4 * 4);
        float4 z4 = *(const float4*)(z + (size_t)(unsigned)c4 * 64 + l4 * 4);
        float4 z5 = *(const float4*)(z + (size_t)(unsigned)c5 * 64 + l4 * 4);
        float4 z6 = *(const float4*)(z + (size_t)(unsigned)c6 * 64 + l4 * 4);
        float4 z7 = *(const float4*)(z + (size_t)(unsigned)c7 * 64 + l4 * 4);
        a0.x += z0.x; a0.y += z0.y; a0.z += z0.z; a0.w += z0.w;
        a1.x += z1.x; a1.y += z1.y; a1.z += z1.z; a1.w += z1.w;
        a2.x += z2.x; a2.y += z2.y; a2.z += z2.z; a2.w += z2.w;
        a3.x += z3.x; a3.y += z3.y; a3.z += z3.z; a3.w += z3.w;
        a0.x += z4.x; a0.y += z4.y; a0.z += z4.z; a0.w += z4.w;
        a1.x += z5.x; a1.y += z5.y; a1.z += z5.z; a1.w += z5.w;
        a2.x += z6.x; a2.y += z6.y; a2.z += z6.z; a2.w += z6.w;
        a3.x += z7.x; a3.y += z7.y; a3.z += z7.z; a3.w += z7.w;
    }
    for (; i + 4 <= end; i += 4) {
        int c0 = __builtin_nontemporal_load(cs + i);
        int c1 = __builtin_nontemporal_load(cs + i + 1);
        int c2 = __builtin_nontemporal_load(cs + i + 2);
        int c3 = __builtin_nontemporal_load(cs + i + 3);
        float4 z0 = *(const float4*)(z + (size_t)(unsigned)c0 * 64 + l4 * 4);
        float4 z1 = *(const float4*)(z + (size_t)(unsigned)c1 * 64 + l4 * 4);
        float4 z2 = *(const float4*)(z + (size_t)(unsigned)c2 * 64 + l4 * 4);
        float4 z3 = *(const float4*)(z + (size_t)(unsigned)c3 * 64 + l4 * 4);
        a0.x += z0.x; a0.y += z0.y; a0.z += z0.z; a0.w += z0.w;
        a1.x += z1.x; a1.y += z1.y; a1.z += z1.z; a1.w += z1.w;
        a2.x += z2.x; a2.y += z2.y; a2.z += z2.z; a2.w += z2.w;
        a3.x += z3.x; a3.y += z3.y; a3.z += z3.z; a3.w += z3.w;
    }
    for (; i < end; ++i) {
        int c = __builtin_nontemporal_load(cs + i);
        float4 zr = *(const float4*)(z + (size_t)(unsigned)c * 64 + l4 * 4);
        a0.x += zr.x; a0.y += zr.y; a0.z += zr.z; a0.w += zr.w;
    }
    const float dn = dinv[n];
    const float4 b4 = *(const float4*)(bias + l4 * 4);
    float4 r;
    r.x = fmaf(dn, (a0.x + a1.x) + (a2.x + a3.x), b4.x);
    r.y = fmaf(dn, (a0.y + a1.y) + (a2.y + a3.y), b4.y);
    r.z = fmaf(dn, (a0.z + a1.z) + (a2.z + a3.z), b4.z);
    r.w = fmaf(dn, (a0.w + a1.w) + (a2.w + a3.w), b4.w);
    r.x = r.x > 0.f ? r.x : 0.f;
    r.y = r.y > 0.f ? r.y : 0.f;
    r.z = r.z > 0.f ? r.z : 0.f;
    r.w = r.w > 0.f ? r.w : 0.f;
    *(float4*)(out + (size_t)n * 64 + l4 * 4) = r;
}

// ---------------- summarize: softmax over layers + hsum + out GEMV ----------------
__global__ __launch_bounds__(256) void k_sum(const float* __restrict__ Hm, const float* __restrict__ scores,
                                             const float* __restrict__ Wout, const float* __restrict__ bout,
                                             float* __restrict__ out) {
    __shared__ float wo[64 * CC];
    __shared__ float hsl[4][64];
    const int t = threadIdx.x;
    for (int i = t; i < (64 * CC) / 4; i += 256) ((float4*)wo)[i] = ((const float4*)Wout)[i];
    __syncthreads();
    const int lane = t & 63;
    const int wid = t >> 6;
    const int n = blockIdx.x * 4 + wid;
    float h0 = Hm[(size_t)(0 * NN + n) * 64 + lane];
    float h1 = Hm[(size_t)(1 * NN + n) * 64 + lane];
    float h2 = Hm[(size_t)(2 * NN + n) * 64 + lane];
    float h3 = Hm[(size_t)(3 * NN + n) * 64 + lane];
    float s0 = scores[0 * NN + n] * 10.f;  // 1/TEMP = 10
    float s1 = scores[1 * NN + n] * 10.f;
    float s2 = scores[2 * NN + n] * 10.f;
    float s3 = scores[3 * NN + n] * 10.f;
    float m = fmaxf(fmaxf(s0, s1), fmaxf(s2, s3));
    float e0 = __expf(s0 - m), e1 = __expf(s1 - m), e2 = __expf(s2 - m), e3 = __expf(s3 - m);
    float inv = 1.f / (e0 + e1 + e2 + e3);
    float hs = (e0 * h0 + e1 * h1 + e2 * h2 + e3 * h3) * inv;
    hsl[wid][lane] = hs;  // wave-synchronous: written and read by the same wave
    float acc = 0.f;
#pragma unroll 8
    for (int d = 0; d < 64; ++d) {
        if (lane < CC) acc = fmaf(hsl[wid][d], wo[d * CC + lane], acc);
    }
    if (lane < CC) out[(size_t)n * CC + lane] = acc + bout[lane];
}

// ---------------- host ----------------
extern "C" void kernel_launch(void* const* d_in, const int* in_sizes, int n_in,
                              void* d_out, int out_size, void* d_ws, size_t ws_size,
                              hipStream_t stream) {
    const float* x    = (const float*)d_in[0];
    const int*   ei   = (const int*)d_in[1];
    const float* W0   = (const float*)d_in[2];
    const float* b0   = (const float*)d_in[3];
    const float* Ws   = (const float*)d_in[4];
    const float* bs   = (const float*)d_in[5];
    const float* Wq   = (const float*)d_in[6];
    const float* Wk   = (const float*)d_in[7];
    const float* Wout = (const float*)d_in[8];
    const float* bout = (const float*)d_in[9];
    float* out = (float*)d_out;

    char* p = (char*)d_ws;
    auto carve = [&](size_t bytes) {
        void* r = (void*)p;
        p += (bytes + 255) & ~(size_t)255;
        return r;
    };
    int*   deg     = (int*)carve((size_t)NN * 4);
    float* dinv    = (float*)carve((size_t)NN * 4);
    int*   row_ptr = (int*)carve((size_t)(NN + 1) * 4);
    int*   cursor  = (int*)carve((size_t)NN * 4);
    int*   bsum    = (int*)carve(256 * 4);
    int*   cs      = (int*)carve((size_t)(EE + NN) * 4);
    float* M       = (float*)carve((size_t)HH * HH * 4);
    float* z       = (float*)carve((size_t)NN * HH * 4);
    float* Hm      = (float*)carve((size_t)4 * NN * HH * 4);
    float* scores  = (float*)carve((size_t)4 * NN * 4);
    (void)ws_size; (void)n_in; (void)in_sizes; (void)out_size;

    const int GB_N  = (NN + 255) / 256;
    const int GB_E4 = (EE / 4 + 255) / 256;            // 1563
    const int GB_F  = (EE / 4 + NN + 255) / 256;       // 1954
    const int GT    = (NN + 63) / 64;                  // 1563
    const int GSC   = (4 * NN) / 64;                   // 6250
    const int GP    = NN / 16;                         // 6250
    const int GS    = NN / 4;                          // 25000

    k_init_deg<<<GB_N, 256, 0, stream>>>(deg);
    k_count<<<GB_E4, 256, 0, stream>>>(ei, deg);
    k_dinv<<<GB_N, 256, 0, stream>>>(deg, dinv);
    k_scanA<<<NB, SCAN_B, 0, stream>>>(deg, row_ptr, bsum);
    k_scanB<<<1, 128, 0, stream>>>(bsum);
    k_scanC<<<NB, SCAN_B, 0, stream>>>(row_ptr, bsum, cursor);
    k_fill<<<GB_F, 256, 0, stream>>>(ei, cursor, cs);
    k_prepM<<<16, 256, 0, stream>>>(Wq, Wk, M);

    k_gemm<FF><<<GT, 256, 0, stream>>>(x, W0, dinv, z, NN);
    k_prop<<<GP, 256, 0, stream>>>(z, row_ptr, cs, dinv, b0, Hm);
    for (int l = 1; l < 4; ++l) {
        k_gemm<HH><<<GT, 256, 0, stream>>>(Hm + (size_t)(l - 1) * NN * HH,
                                           Ws + (size_t)(l - 1) * HH * HH, dinv, z, NN);
        k_prop<<<GP, 256, 0, stream>>>(z, row_ptr, cs, dinv, bs + (size_t)(l - 1) * HH,
                                       Hm + (size_t)l * NN * HH);
    }

    k_score<<<GSC, 256, 0, stream>>>(Hm, M, scores);
    k_sum<<<GS, 256, 0, stream>>>(Hm, scores, Wout, bout, out);
}

// Round 6
// 716.083 us; speedup vs baseline: 1.6098x; 1.0635x over previous
//
#include <hip/hip_runtime.h>
#include <hip/hip_bf16.h>
#include <math.h>

#define NN 100000
#define EE 1600000
#define FF 128
#define HH 64
#define CC 40

constexpr int SCAN_B = 1024;
constexpr int NB = (NN + SCAN_B - 1) / SCAN_B;  // 98

// XCD-local scatter geometry: 8 groups (≈XCDs) × FB blocks; each group owns RN nodes.
constexpr int RN = NN / 8;        // 12500 nodes per group
constexpr int FB = 128;           // blocks per group
constexpr int CHUNK = EE / FB;    // 12500 edges per block-slice
constexpr int SELFB = (RN + FB - 1) / FB;  // 98 self-loops per block

// ---------------- degree / norm ----------------
__global__ void k_init_deg(int* __restrict__ deg) {
    int i = blockIdx.x * 256 + threadIdx.x;
    if (i < NN) deg[i] = 1;  // self-loop contributes 1
}

// group-filtered count: group g only counts dst in its node range -> XCD-local atomics
__global__ void k_count(const int* __restrict__ ei, int* __restrict__ deg) {
    const int g = blockIdx.x & 7;
    const int j = blockIdx.x >> 3;
    const int lo = g * RN, hi = lo + RN;
    const int* __restrict__ dstp = ei + EE;
    const int e1 = (j + 1) * CHUNK;
    for (int e = j * CHUNK + threadIdx.x; e < e1; e += 256) {
        int d = dstp[e];
        if (d >= lo && d < hi) atomicAdd(&deg[d], 1);
    }
}

__global__ void k_dinv(const int* __restrict__ deg, float* __restrict__ dinv) {
    int i = blockIdx.x * 256 + threadIdx.x;
    if (i < NN) dinv[i] = rsqrtf((float)deg[i]);  // deg >= 1 always
}

// ---------------- exclusive scan (3-kernel) ----------------
__global__ void k_scanA(const int* __restrict__ deg, int* __restrict__ excl, int* __restrict__ bsum) {
    __shared__ int s[SCAN_B];
    int t = threadIdx.x;
    int g = blockIdx.x * SCAN_B + t;
    int v = (g < NN) ? deg[g] : 0;
    s[t] = v;
    __syncthreads();
    for (int o = 1; o < SCAN_B; o <<= 1) {
        int u = (t >= o) ? s[t - o] : 0;
        __syncthreads();
        s[t] += u;
        __syncthreads();
    }
    if (g < NN) excl[g] = s[t] - v;
    if (t == SCAN_B - 1) bsum[blockIdx.x] = s[t];
}

__global__ void k_scanB(int* __restrict__ bsum) {
    __shared__ int s[128];
    int t = threadIdx.x;
    int v = (t < NB) ? bsum[t] : 0;
    s[t] = v;
    __syncthreads();
    for (int o = 1; o < 128; o <<= 1) {
        int u = (t >= o) ? s[t - o] : 0;
        __syncthreads();
        s[t] += u;
        __syncthreads();
    }
    if (t < NB) bsum[t] = s[t] - v;  // exclusive block offsets
}

__global__ void k_scanC(int* __restrict__ rp, const int* __restrict__ bsum, int* __restrict__ cursor) {
    int t = threadIdx.x;
    int g = blockIdx.x * SCAN_B + t;
    if (g < NN) {
        int v = rp[g] + bsum[blockIdx.x];
        rp[g] = v;
        cursor[g] = v;
    }
    if (g == 0) rp[NN] = EE + NN;
}

// ---------------- CSR fill: XCD-local group-filtered scatter ----------------
// Group g (== blockIdx.x & 7, round-robin -> same XCD) handles only dst in
// [g*RN, (g+1)*RN): its cursor slice (50KB) and cs output slice (~830KB) stay
// resident in that XCD's L2, so the 16 stores per 64B line merge before
// writeback (R5 showed 113MB WRITE_SIZE = zero merging with global scatter).
// Plain stores (NOT nontemporal: nt evicts early and defeats merging).
__global__ void k_fill(const int* __restrict__ ei, int* __restrict__ cursor, int* __restrict__ cs) {
    const int g = blockIdx.x & 7;
    const int j = blockIdx.x >> 3;
    const int lo = g * RN, hi = lo + RN;
    const int* __restrict__ dstp = ei + EE;
    const int e1 = (j + 1) * CHUNK;
    for (int e = j * CHUNK + threadIdx.x; e < e1; e += 256) {
        int d = dstp[e];
        if (d >= lo && d < hi) {
            int s = ei[e];
            int p = atomicAdd(&cursor[d], 1);
            cs[p] = s;
        }
    }
    // self-loops for this group's nodes, spread across the group's blocks
    int n = lo + j * SELFB + threadIdx.x;
    if (threadIdx.x < SELFB && n < hi) {
        int p = atomicAdd(&cursor[n], 1);
        cs[p] = n;
    }
}

// ---------------- dense GEMM: Z[r,:] = dinv[r] * (A[r,:] @ W)  ----------------
template <int K>
__global__ __launch_bounds__(256) void k_gemm(const float* __restrict__ A, const float* __restrict__ W,
                                              const float* __restrict__ dinv, float* __restrict__ Z,
                                              int nrows) {
    constexpr int S = 68;  // LDS stride: bank-spread, 16B-aligned
    __shared__ float wl[64 * 64];
    __shared__ float hl[64 * S];
    const int t = threadIdx.x;
    const int r0 = blockIdx.x * 64;
    const int rg = t >> 4, cg = t & 15;
    float acc[4][4] = {};

    for (int kb = 0; kb < K; kb += 64) {
        {
            const float4* Wv = (const float4*)(W + kb * 64);
            for (int i = t; i < 1024; i += 256) ((float4*)wl)[i] = Wv[i];
        }
        for (int i = t; i < 1024; i += 256) {
            int row = i >> 4, d4 = i & 15;
            float4 v = {0.f, 0.f, 0.f, 0.f};
            if (r0 + row < nrows) v = *(const float4*)(A + (size_t)(r0 + row) * K + kb + d4 * 4);
            *(float4*)(hl + row * S + d4 * 4) = v;
        }
        __syncthreads();
#pragma unroll 8
        for (int d = 0; d < 64; ++d) {
            float4 w4 = *(const float4*)(wl + d * 64 + cg * 4);
#pragma unroll
            for (int i = 0; i < 4; i++) {
                float h = hl[(rg * 4 + i) * S + d];
                acc[i][0] = fmaf(h, w4.x, acc[i][0]);
                acc[i][1] = fmaf(h, w4.y, acc[i][1]);
                acc[i][2] = fmaf(h, w4.z, acc[i][2]);
                acc[i][3] = fmaf(h, w4.w, acc[i][3]);
            }
        }
        __syncthreads();
    }
#pragma unroll
    for (int i = 0; i < 4; i++) {
        int row = r0 + rg * 4 + i;
        if (row < nrows) {
            float dv = dinv[row];
            float4 o = {acc[i][0] * dv, acc[i][1] * dv, acc[i][2] * dv, acc[i][3] * dv};
            *(float4*)(Z + (size_t)row * 64 + cg * 4) = o;
        }
    }
}

// ---------------- M = Wq @ Wk^T (64x64), 16 blocks x 4 rows ----------------
__global__ __launch_bounds__(256) void k_prepM(const float* __restrict__ Wq, const float* __restrict__ Wk,
                                               float* __restrict__ M) {
    __shared__ float wk[64 * 65];
    __shared__ float wq[4 * 64];
    const int t = threadIdx.x;
    for (int i = t; i < 1024; i += 256) {
        int r = i >> 4, c4 = i & 15;
        float4 v = ((const float4*)Wk)[i];
        wk[r * 65 + c4 * 4 + 0] = v.x;
        wk[r * 65 + c4 * 4 + 1] = v.y;
        wk[r * 65 + c4 * 4 + 2] = v.z;
        wk[r * 65 + c4 * 4 + 3] = v.w;
    }
    const int rbase = blockIdx.x * 4;
    wq[t] = Wq[rbase * 64 + t];
    __syncthreads();
    const int rr = t >> 6;  // 0..3
    const int c = t & 63;
    float acc = 0.f;
#pragma unroll 8
    for (int e = 0; e < 64; ++e) acc = fmaf(wq[rr * 64 + e], wk[c * 65 + e], acc);
    M[(rbase + rr) * 64 + c] = acc;  // M[d][d'] = dot(Wq row d, Wk row d')
}

// ---------------- scores[r] = h_r @ M @ h_r^T (one GEMM + fused dot) ----------------
__global__ __launch_bounds__(256) void k_score(const float* __restrict__ Hm, const float* __restrict__ M,
                                               float* __restrict__ scores) {
    constexpr int S = 68;
    __shared__ float wl[4096];
    __shared__ float hl[64 * S];
    const int t = threadIdx.x;
    const int r0 = blockIdx.x * 64;  // 4N = 400000 = 6250*64, no tail
    for (int i = t; i < 1024; i += 256) ((float4*)wl)[i] = ((const float4*)M)[i];
    for (int i = t; i < 1024; i += 256) {
        int row = i >> 4, d4 = i & 15;
        *(float4*)(hl + row * S + d4 * 4) = *(const float4*)(Hm + (size_t)(r0 + row) * 64 + d4 * 4);
    }
    __syncthreads();
    const int rg = t >> 4, cg = t & 15;
    float u[4][4] = {};
#pragma unroll 8
    for (int d = 0; d < 64; ++d) {
        float4 m4 = *(const float4*)(wl + d * 64 + cg * 4);
#pragma unroll
        for (int i = 0; i < 4; i++) {
            float h = hl[(rg * 4 + i) * S + d];
            u[i][0] = fmaf(h, m4.x, u[i][0]);
            u[i][1] = fmaf(h, m4.y, u[i][1]);
            u[i][2] = fmaf(h, m4.z, u[i][2]);
            u[i][3] = fmaf(h, m4.w, u[i][3]);
        }
    }
#pragma unroll
    for (int i = 0; i < 4; i++) {
        const float* hrow = hl + (rg * 4 + i) * S + cg * 4;
        float p = u[i][0] * hrow[0] + u[i][1] * hrow[1] + u[i][2] * hrow[2] + u[i][3] * hrow[3];
        p += __shfl_xor(p, 1);
        p += __shfl_xor(p, 2);
        p += __shfl_xor(p, 4);
        p += __shfl_xor(p, 8);
        if (cg == 0) scores[r0 + rg * 4 + i] = p;  // raw q.k (TEMP applied later)
    }
}

// ---------------- propagate: out[n] = relu(dinv[n]*sum_e z'[col] + bias) ----------------
// z' is pre-scaled by dinv[src] in the gemm epilogue -> pure gather-sum here.
// 16 lanes/node (float4), 4 nodes/wave, unroll-8 -> 32 row-gathers in flight/wave.
__global__ __launch_bounds__(256) void k_prop(const float* __restrict__ z, const int* __restrict__ rp,
                                              const int* __restrict__ cs, const float* __restrict__ dinv,
                                              const float* __restrict__ bias, float* __restrict__ out) {
    const int lane = threadIdx.x & 63;
    const int g = lane >> 4;    // node group within wave (0..3)
    const int l4 = lane & 15;   // float4 slot within row
    const int n = blockIdx.x * 16 + (threadIdx.x >> 6) * 4 + g;  // grid covers N exactly
    const int beg = rp[n], end = rp[n + 1];
    float4 a0 = {0, 0, 0, 0}, a1 = {0, 0, 0, 0}, a2 = {0, 0, 0, 0}, a3 = {0, 0, 0, 0};
    int i = beg;
    for (; i + 8 <= end; i += 8) {
        int c0 = __builtin_nontemporal_load(cs + i);
        int c1 = __builtin_nontemporal_load(cs + i + 1);
        int c2 = __builtin_nontemporal_load(cs + i + 2);
        int c3 = __builtin_nontemporal_load(cs + i + 3);
        int c4 = __builtin_nontemporal_load(cs + i + 4);
        int c5 = __builtin_nontemporal_load(cs + i + 5);
        int c6 = __builtin_nontemporal_load(cs + i + 6);
        int c7 = __builtin_nontemporal_load(cs + i + 7);
        float4 z0 = *(const float4*)(z + (size_t)(unsigned)c0 * 64 + l4 * 4);
        float4 z1 = *(const float4*)(z + (size_t)(unsigned)c1 * 64 + l4 * 4);
        float4 z2 = *(const float4*)(z + (size_t)(unsigned)c2 * 64 + l4 * 4);
        float4 z3 = *(const float4*)(z + (size_t)(unsigned)c3 * 64 + l4 * 4);
        float4 z4 = *(const float4*)(z + (size_t)(unsigned)c4 * 64 + l4 * 4);
        float4 z5 = *(const float4*)(z + (size_t)(unsigned)c5 * 64 + l4 * 4);
        float4 z6 = *(const float4*)(z + (size_t)(unsigned)c6 * 64 + l4 * 4);
        float4 z7 = *(const float4*)(z + (size_t)(unsigned)c7 * 64 + l4 * 4);
        a0.x += z0.x; a0.y += z0.y; a0.z += z0.z; a0.w += z0.w;
        a1.x += z1.x; a1.y += z1.y; a1.z += z1.z; a1.w += z1.w;
        a2.x += z2.x; a2.y += z2.y; a2.z += z2.z; a2.w += z2.w;
        a3.x += z3.x; a3.y += z3.y; a3.z += z3.z; a3.w += z3.w;
        a0.x += z4.x; a0.y += z4.y; a0.z += z4.z; a0.w += z4.w;
        a1.x += z5.x; a1.y += z5.y; a1.z += z5.z; a1.w += z5.w;
        a2.x += z6.x; a2.y += z6.y; a2.z += z6.z; a2.w += z6.w;
        a3.x += z7.x; a3.y += z7.y; a3.z += z7.z; a3.w += z7.w;
    }
    for (; i + 4 <= end; i += 4) {
        int c0 = __builtin_nontemporal_load(cs + i);
        int c1 = __builtin_nontemporal_load(cs + i + 1);
        int c2 = __builtin_nontemporal_load(cs + i + 2);
        int c3 = __builtin_nontemporal_load(cs + i + 3);
        float4 z0 = *(const float4*)(z + (size_t)(unsigned)c0 * 64 + l4 * 4);
        float4 z1 = *(const float4*)(z + (size_t)(unsigned)c1 * 64 + l4 * 4);
        float4 z2 = *(const float4*)(z + (size_t)(unsigned)c2 * 64 + l4 * 4);
        float4 z3 = *(const float4*)(z + (size_t)(unsigned)c3 * 64 + l4 * 4);
        a0.x += z0.x; a0.y += z0.y; a0.z += z0.z; a0.w += z0.w;
        a1.x += z1.x; a1.y += z1.y; a1.z += z1.z; a1.w += z1.w;
        a2.x += z2.x; a2.y += z2.y; a2.z += z2.z; a2.w += z2.w;
        a3.x += z3.x; a3.y += z3.y; a3.z += z3.z; a3.w += z3.w;
    }
    for (; i < end; ++i) {
        int c = __builtin_nontemporal_load(cs + i);
        float4 zr = *(const float4*)(z + (size_t)(unsigned)c * 64 + l4 * 4);
        a0.x += zr.x; a0.y += zr.y; a0.z += zr.z; a0.w += zr.w;
    }
    const float dn = dinv[n];
    const float4 b4 = *(const float4*)(bias + l4 * 4);
    float4 r;
    r.x = fmaf(dn, (a0.x + a1.x) + (a2.x + a3.x), b4.x);
    r.y = fmaf(dn, (a0.y + a1.y) + (a2.y + a3.y), b4.y);
    r.z = fmaf(dn, (a0.z + a1.z) + (a2.z + a3.z), b4.z);
    r.w = fmaf(dn, (a0.w + a1.w) + (a2.w + a3.w), b4.w);
    r.x = r.x > 0.f ? r.x : 0.f;
    r.y = r.y > 0.f ? r.y : 0.f;
    r.z = r.z > 0.f ? r.z : 0.f;
    r.w = r.w > 0.f ? r.w : 0.f;
    *(float4*)(out + (size_t)n * 64 + l4 * 4) = r;
}

// ---------------- summarize: softmax over layers + hsum + out GEMV ----------------
__global__ __launch_bounds__(256) void k_sum(const float* __restrict__ Hm, const float* __restrict__ scores,
                                             const float* __restrict__ Wout, const float* __restrict__ bout,
                                             float* __restrict__ out) {
    __shared__ float wo[64 * CC];
    __shared__ float hsl[4][64];
    const int t = threadIdx.x;
    for (int i = t; i < (64 * CC) / 4; i += 256) ((float4*)wo)[i] = ((const float4*)Wout)[i];
    __syncthreads();
    const int lane = t & 63;
    const int wid = t >> 6;
    const int n = blockIdx.x * 4 + wid;
    float h0 = Hm[(size_t)(0 * NN + n) * 64 + lane];
    float h1 = Hm[(size_t)(1 * NN + n) * 64 + lane];
    float h2 = Hm[(size_t)(2 * NN + n) * 64 + lane];
    float h3 = Hm[(size_t)(3 * NN + n) * 64 + lane];
    float s0 = scores[0 * NN + n] * 10.f;  // 1/TEMP = 10
    float s1 = scores[1 * NN + n] * 10.f;
    float s2 = scores[2 * NN + n] * 10.f;
    float s3 = scores[3 * NN + n] * 10.f;
    float m = fmaxf(fmaxf(s0, s1), fmaxf(s2, s3));
    float e0 = __expf(s0 - m), e1 = __expf(s1 - m), e2 = __expf(s2 - m), e3 = __expf(s3 - m);
    float inv = 1.f / (e0 + e1 + e2 + e3);
    float hs = (e0 * h0 + e1 * h1 + e2 * h2 + e3 * h3) * inv;
    hsl[wid][lane] = hs;  // wave-synchronous: written and read by the same wave
    float acc = 0.f;
#pragma unroll 8
    for (int d = 0; d < 64; ++d) {
        if (lane < CC) acc = fmaf(hsl[wid][d], wo[d * CC + lane], acc);
    }
    if (lane < CC) out[(size_t)n * CC + lane] = acc + bout[lane];
}

// ---------------- host ----------------
extern "C" void kernel_launch(void* const* d_in, const int* in_sizes, int n_in,
                              void* d_out, int out_size, void* d_ws, size_t ws_size,
                              hipStream_t stream) {
    const float* x    = (const float*)d_in[0];
    const int*   ei   = (const int*)d_in[1];
    const float* W0   = (const float*)d_in[2];
    const float* b0   = (const float*)d_in[3];
    const float* Ws   = (const float*)d_in[4];
    const float* bs   = (const float*)d_in[5];
    const float* Wq   = (const float*)d_in[6];
    const float* Wk   = (const float*)d_in[7];
    const float* Wout = (const float*)d_in[8];
    const float* bout = (const float*)d_in[9];
    float* out = (float*)d_out;

    char* p = (char*)d_ws;
    auto carve = [&](size_t bytes) {
        void* r = (void*)p;
        p += (bytes + 255) & ~(size_t)255;
        return r;
    };
    int*   deg     = (int*)carve((size_t)NN * 4);
    float* dinv    = (float*)carve((size_t)NN * 4);
    int*   row_ptr = (int*)carve((size_t)(NN + 1) * 4);
    int*   cursor  = (int*)carve((size_t)NN * 4);
    int*   bsum    = (int*)carve(256 * 4);
    int*   cs      = (int*)carve((size_t)(EE + NN) * 4);
    float* M       = (float*)carve((size_t)HH * HH * 4);
    float* z       = (float*)carve((size_t)NN * HH * 4);
    float* Hm      = (float*)carve((size_t)4 * NN * HH * 4);
    float* scores  = (float*)carve((size_t)4 * NN * 4);
    (void)ws_size; (void)n_in; (void)in_sizes; (void)out_size;

    const int GB_N  = (NN + 255) / 256;
    const int GFILL = FB * 8;                          // 1024 group-filter blocks
    const int GT    = (NN + 63) / 64;                  // 1563
    const int GSC   = (4 * NN) / 64;                   // 6250
    const int GP    = NN / 16;                         // 6250
    const int GS    = NN / 4;                          // 25000

    k_init_deg<<<GB_N, 256, 0, stream>>>(deg);
    k_count<<<GFILL, 256, 0, stream>>>(ei, deg);
    k_dinv<<<GB_N, 256, 0, stream>>>(deg, dinv);
    k_scanA<<<NB, SCAN_B, 0, stream>>>(deg, row_ptr, bsum);
    k_scanB<<<1, 128, 0, stream>>>(bsum);
    k_scanC<<<NB, SCAN_B, 0, stream>>>(row_ptr, bsum, cursor);
    k_fill<<<GFILL, 256, 0, stream>>>(ei, cursor, cs);
    k_prepM<<<16, 256, 0, stream>>>(Wq, Wk, M);

    k_gemm<FF><<<GT, 256, 0, stream>>>(x, W0, dinv, z, NN);
    k_prop<<<GP, 256, 0, stream>>>(z, row_ptr, cs, dinv, b0, Hm);
    for (int l = 1; l < 4; ++l) {
        k_gemm<HH><<<GT, 256, 0, stream>>>(Hm + (size_t)(l - 1) * NN * HH,
                                           Ws + (size_t)(l - 1) * HH * HH, dinv, z, NN);
        k_prop<<<GP, 256, 0, stream>>>(z, row_ptr, cs, dinv, bs + (size_t)(l - 1) * HH,
                                       Hm + (size_t)l * NN * HH);
    }

    k_score<<<GSC, 256, 0, stream>>>(Hm, M, scores);
    k_sum<<<GS, 256, 0, stream>>>(Hm, scores, Wout, bout, out);
}